// Round 8
// baseline (1164.721 us; speedup 1.0000x reference)
//
#include <hip/hip_runtime.h>
#include <hip/hip_bf16.h>
#include <stdint.h>

// ---------------------------------------------------------------------------
// Problem geometry
//   x (4,400,128) -> conv1d(200->512,k3,p1,relu) -> conv1d(512->128,k3,p1,relu) = h
//   x4 = sigmoid(0.01*conv1d(h, w3(3,128,1))) -> outputs xc(ch2), xb_start(ch0), xb_end(ch1)
//   cm = einsum('bct,tm->bcm', h, mask) ; conv3d(w3d, stride 32) + b3d, relu
//     == relu(b3d[o] + sum_{s,t} mask[t,s,i,j] * H2[b,o,s,t]),
//        H2[b,o,s,t] = sum_c w3d[o,c,s] * h[b,c,t]      (mask: <=6 taps per (s,i,j))
//   then 1x1(512->128,relu), 3x3(128->64,relu), 3x3(64->64,relu), 1x1(64->4,sigmoid)
//   outputs (float32): xc,xb_start,xb_end (3*512) | iou (4,2,128,128) | prop_start | prop_end
//
// cm stored TRANSPOSED: cm2[ij][bo]. k_bm: single-wave blocks, bo-QUAD per
// thread (dwordx2 = 4 bf16 = 4 MACs), taps via wave-uniform (scalar) loads,
// no LDS, grid (x=boT 8 -> XCD-pinned 2MB h2t slice, y = i*8 + oct).
// ---------------------------------------------------------------------------

typedef unsigned int uint32;

__device__ __forceinline__ float bf2f(ushort u) {
    return __uint_as_float(((uint32)u) << 16);
}
__device__ __forceinline__ ushort f2bf(float f) {
    uint32 x = __float_as_uint(f);
    uint32 r = (x + 0x7FFFu + ((x >> 16) & 1u)) >> 16;
    return (ushort)r;
}
__device__ __forceinline__ float sigmoidf(float x) {
    return 1.0f / (1.0f + __expf(-x));
}

// ---------------------------------------------------------------------------
// conv1d (k=3, pad=1, relu). Block: 16 out-channels x 128 t. Grid (COUT/16, B).
// ---------------------------------------------------------------------------
__global__ __launch_bounds__(256) void k_conv1d_relu(
    const float* __restrict__ in, const float* __restrict__ w,
    const float* __restrict__ bias, float* __restrict__ out,
    int CIN, int in_batch_stride, int COUT)
{
    __shared__ float lx[64 * 132];   // [c][0..127 data, 128 = zero pad]
    int b  = blockIdx.y;
    int o  = blockIdx.x * 16 + (threadIdx.x >> 4);
    int tg = threadIdx.x & 15;
    int t0 = tg * 8;

    float acc[8];
#pragma unroll
    for (int k = 0; k < 8; ++k) acc[k] = 0.0f;

    for (int c0 = 0; c0 < CIN; c0 += 64) {
        int nc = CIN - c0; if (nc > 64) nc = 64;
        __syncthreads();
        for (int n = threadIdx.x; n < nc * 32; n += 256) {
            int cl = n >> 5, q = n & 31;
            float4 v = *(const float4*)(in + ((size_t)(b * in_batch_stride + c0 + cl)) * 128 + q * 4);
            *(float4*)(&lx[cl * 132 + q * 4]) = v;
        }
        for (int cl = threadIdx.x; cl < nc; cl += 256) lx[cl * 132 + 128] = 0.0f;
        __syncthreads();

        for (int cl = 0; cl < nc; ++cl) {
            int c = c0 + cl;
            const float* wp = w + ((size_t)o * CIN + c) * 3;
            float w0 = wp[0], w1 = wp[1], w2 = wp[2];
            const float* row = &lx[cl * 132];
            float xv[10];
            if (t0 == 0) {
                xv[0] = 0.0f;
#pragma unroll
                for (int k = 1; k < 10; ++k) xv[k] = row[k - 1];
            } else {
#pragma unroll
                for (int k = 0; k < 10; ++k) xv[k] = row[t0 - 1 + k];
            }
#pragma unroll
            for (int k = 0; k < 8; ++k)
                acc[k] += w0 * xv[k] + w1 * xv[k + 1] + w2 * xv[k + 2];
        }
    }
    float bo = bias[o];
#pragma unroll
    for (int k = 0; k < 8; ++k) {
        float v = acc[k] + bo;
        out[((size_t)(b * COUT + o)) * 128 + t0 + k] = v > 0.0f ? v : 0.0f;
    }
}

// ---------------------------------------------------------------------------
// x4 head -> d_out[0:1536] floats: (xc=ch2 | xb_start=ch0 | xb_end=ch1)
// ---------------------------------------------------------------------------
__global__ void k_x4(const float* __restrict__ h, const float* __restrict__ w3,
                     const float* __restrict__ b3, float* __restrict__ outp)
{
    int tid = threadIdx.x;
    int b = tid >> 7, t = tid & 127;
    float a0 = 0.f, a1 = 0.f, a2 = 0.f;
    for (int c = 0; c < 128; ++c) {
        float hv = h[((size_t)(b * 128 + c)) * 128 + t];
        a0 += w3[c] * hv;
        a1 += w3[128 + c] * hv;
        a2 += w3[256 + c] * hv;
    }
    float s0 = sigmoidf(0.01f * (a0 + b3[0]));
    float s1 = sigmoidf(0.01f * (a1 + b3[1]));
    float s2 = sigmoidf(0.01f * (a2 + b3[2]));
    int bt = b * 128 + t;
    outp[bt]        = s2;   // xc
    outp[512 + bt]  = s0;   // xb_start
    outp[1024 + bt] = s1;   // xb_end
}

// ---------------------------------------------------------------------------
// H2t[(s*128+t)*2048 + b*512+o] = bf16( sum_c w3d[o,c,s]*h[b,c,t] )
// ---------------------------------------------------------------------------
__global__ __launch_bounds__(256) void k_h2(
    const float* __restrict__ h, const float* __restrict__ w3d,
    ushort* __restrict__ h2t)
{
    __shared__ float lw[64 * 129];     // [o][c]
    __shared__ float lhs[32 * 132];    // [c_local][t] ; reused as ushort out stage
    int ot = blockIdx.x, s = blockIdx.y, b = blockIdx.z;
    int o0 = ot * 64;

    for (int n = threadIdx.x; n < 8192; n += 256) {
        int o = n >> 7, c = n & 127;
        lw[o * 129 + c] = w3d[(size_t)(o0 + o) * 4096 + c * 32 + s];
    }

    int og = threadIdx.x >> 4, tg = threadIdx.x & 15;
    int o0t = og * 4, t0 = tg * 8;
    float acc[4][8];
#pragma unroll
    for (int oo = 0; oo < 4; ++oo)
#pragma unroll
        for (int k = 0; k < 8; ++k) acc[oo][k] = 0.0f;

    for (int c0 = 0; c0 < 128; c0 += 32) {
        __syncthreads();
        for (int n = threadIdx.x; n < 1024; n += 256) {
            int cl = n >> 5, q = n & 31;
            *(float4*)(&lhs[cl * 132 + q * 4]) =
                *(const float4*)(h + ((size_t)(b * 128 + c0 + cl)) * 128 + q * 4);
        }
        __syncthreads();
        for (int cl = 0; cl < 32; ++cl) {
            float hv[8];
#pragma unroll
            for (int k = 0; k < 8; ++k) hv[k] = lhs[cl * 132 + t0 + k];
#pragma unroll
            for (int oo = 0; oo < 4; ++oo) {
                float wv = lw[(o0t + oo) * 129 + c0 + cl];
#pragma unroll
                for (int k = 0; k < 8; ++k) acc[oo][k] += wv * hv[k];
            }
        }
    }
    __syncthreads();
    ushort* lout = (ushort*)lhs;       // [t*64 + o]
#pragma unroll
    for (int oo = 0; oo < 4; ++oo)
#pragma unroll
        for (int k = 0; k < 8; ++k)
            lout[(t0 + k) * 64 + o0t + oo] = f2bf(acc[oo][k]);
    __syncthreads();
    for (int n = threadIdx.x; n < 8192; n += 256) {
        int t = n >> 6, o = n & 63;
        h2t[(size_t)(s * 128 + t) * 2048 + b * 512 + o0 + o] = lout[n];
    }
}

// ---------------------------------------------------------------------------
// E1: per mask column m=(s,i,j), collect nonzero (t,w) taps (<=6 exist, cap 8).
// ---------------------------------------------------------------------------
__global__ __launch_bounds__(256) void k_e1(
    const float* __restrict__ mask, uint32* __restrict__ ecnt,
    uint8_t* __restrict__ et, float* __restrict__ ew)
{
    uint32 m = blockIdx.x * 256 + threadIdx.x;
    int cnt = 0;
    for (int t = 0; t < 128; ++t) {
        float w = mask[(size_t)t * 524288 + m];
        if (w != 0.0f) {
            if (cnt < 8) {
                et[(size_t)m * 8 + cnt] = (uint8_t)t;
                ew[(size_t)m * 8 + cnt] = w;
            }
            cnt++;
        }
    }
    ecnt[m] = (uint32)(cnt < 8 ? cnt : 8);
}

// ---------------------------------------------------------------------------
// E2: merge per (i,j): taps over all 32 s -> packed {w_bits, byte_off} (<=192).
// byte_off = st * 4096 (h2t row pitch in bytes) so k_bm's inner loop is lean.
// ---------------------------------------------------------------------------
__global__ void k_e2(const uint32* __restrict__ ecnt, const uint8_t* __restrict__ et,
                     const float* __restrict__ ew, uint32* __restrict__ cntij,
                     int2* __restrict__ taps)
{
    int lane = threadIdx.x & 31;
    int col = blockIdx.x * 2 + (threadIdx.x >> 5);
    uint32 m = (uint32)lane * 16384u + (uint32)col;
    int c = (int)ecnt[m];
    int v = c;
    for (int d = 1; d < 32; d <<= 1) {
        int t = __shfl_up(v, d, 32);
        if (lane >= d) v += t;
    }
    int off = v - c;
    if (lane == 31) cntij[col] = (uint32)v;
    for (int k = 0; k < c; ++k) {
        int2 r;
        r.x = __float_as_int(ew[(size_t)m * 8 + k]);
        r.y = ((lane << 7) + (int)et[(size_t)m * 8 + k]) << 12;   // st * 4096 bytes
        taps[(size_t)col * 192 + off + k] = r;
    }
}

// ---------------------------------------------------------------------------
// k_wt: transpose conv3x3 weights (COUT=64, CIN, 3, 3) -> wT[(cin*9+kk)*64+cout]
// so k_conv3x3 weight staging is a contiguous, div-free copy.
// ---------------------------------------------------------------------------
__global__ __launch_bounds__(256) void k_wt(
    const float* __restrict__ w, float* __restrict__ wT, int CIN)
{
    int n = blockIdx.x * 256 + threadIdx.x;
    int total = 64 * CIN * 9;
    if (n >= total) return;
    int per = CIN * 9;
    int cout = n / per;
    int rem = n - cout * per;     // cin*9 + kk
    wT[(size_t)rem * 64 + cout] = w[n];
}

// ---------------------------------------------------------------------------
// k_bm: cm2[ij, bo] = relu(b3d[o] + sum_taps w * H2t[st, bo])   (bf16 out)
// Single-wave blocks (64 thr), thread owns bo-quad (dwordx2 = 4 bf16/tap).
// Tap list + counts read via wave-uniform addresses -> scalar loads, no LDS,
// no barriers. Grid (x=boT 8, y = i*8 + oct): x fastest pins each 2MB h2t
// bo-slice to one XCD's L2; 8192 single-wave blocks = 32 waves/CU.
// ---------------------------------------------------------------------------
__global__ __launch_bounds__(64) void k_bm(
    const ushort* __restrict__ h2t, const int2* __restrict__ taps,
    const uint32* __restrict__ cntij, const float* __restrict__ b3d,
    ushort* __restrict__ cm2)
{
    int boT = blockIdx.x;
    int i = blockIdx.y >> 3, oc = blockIdx.y & 7;
    int tid = threadIdx.x;
    int bo0 = boT * 256 + tid * 4;
    const char* hb = (const char*)h2t + (size_t)bo0 * 2;
    float4 bias = *(const float4*)(b3d + (bo0 & 511));
    int ij0 = i * 128 + oc * 16;

#pragma unroll 1
    for (int c = 0; c < 16; ++c) {
        int ij = ij0 + c;
        int cnt = (int)cntij[ij];                    // uniform -> s_load
        const int2* tp = taps + (size_t)ij * 192;    // uniform base
        float a0 = 0.f, a1 = 0.f, a2 = 0.f, a3 = 0.f;
#pragma unroll 4
        for (int k = 0; k < cnt; ++k) {
            int2 r = tp[k];                          // uniform -> s_load_dwordx2
            uint2 hv = *(const uint2*)(hb + (uint32)r.y);
            float w = __int_as_float(r.x);
            a0 += w * __uint_as_float(hv.x << 16);
            a1 += w * __uint_as_float(hv.x & 0xffff0000u);
            a2 += w * __uint_as_float(hv.y << 16);
            a3 += w * __uint_as_float(hv.y & 0xffff0000u);
        }
        float v0 = fmaxf(a0 + bias.x, 0.f);
        float v1 = fmaxf(a1 + bias.y, 0.f);
        float v2 = fmaxf(a2 + bias.z, 0.f);
        float v3 = fmaxf(a3 + bias.w, 0.f);
        uint64_t pr = (uint64_t)((uint32)f2bf(v0) | ((uint32)f2bf(v1) << 16))
                    | ((uint64_t)((uint32)f2bf(v2) | ((uint32)f2bf(v3) << 16)) << 32);
        __builtin_nontemporal_store(pr, (uint64_t*)(cm2 + (size_t)ij * 2048 + bo0));
    }
}

// ---------------------------------------------------------------------------
// conv-a: 1x1, 512 -> 128, relu.  Reads cm2[ij][bo] layout.
// p1[b,c,ij] = relu(ba[c] + sum_o wa[c,o]*cm2[ij, b*512+o])
// ---------------------------------------------------------------------------
__global__ __launch_bounds__(256) void k_conva(
    const ushort* __restrict__ cm2, const float* __restrict__ wa,
    const float* __restrict__ ba, float* __restrict__ p1)
{
    __shared__ float lx[32 * 132];   // [oo][j]
    __shared__ float lwv[32 * 132];  // [oo][c]
    int i = blockIdx.x, b = blockIdx.y;
    int cg = threadIdx.x >> 4, jg = threadIdx.x & 15;
    int c0 = cg * 8, j0 = jg * 8;
    float acc[8][8];
#pragma unroll
    for (int cc = 0; cc < 8; ++cc)
#pragma unroll
        for (int k = 0; k < 8; ++k) acc[cc][k] = 0.0f;

    for (int o0 = 0; o0 < 512; o0 += 32) {
        __syncthreads();
        // stage 128 j x 32 o from cm2[(i*128+j)*2048 + b*512 + o0 + *]
        for (int n = threadIdx.x; n < 2048; n += 256) {
            int j = n >> 4, q = n & 15;            // q = o-pair index
            uint32 v = *(const uint32*)(cm2 + ((size_t)(i * 128 + j)) * 2048 + b * 512 + o0 + 2 * q);
            lx[(2 * q) * 132 + j]     = bf2f((ushort)(v & 0xffffu));
            lx[(2 * q + 1) * 132 + j] = bf2f((ushort)(v >> 16));
        }
        for (int n = threadIdx.x; n < 4096; n += 256) {
            int oo = n & 31, c = n >> 5;
            lwv[oo * 132 + c] = wa[(size_t)c * 512 + o0 + oo];
        }
        __syncthreads();
        for (int oo = 0; oo < 32; ++oo) {
            float xv[8], wvv[8];
#pragma unroll
            for (int k = 0; k < 8; ++k) xv[k] = lx[oo * 132 + j0 + k];
#pragma unroll
            for (int k = 0; k < 8; ++k) wvv[k] = lwv[oo * 132 + c0 + k];
#pragma unroll
            for (int cc = 0; cc < 8; ++cc)
#pragma unroll
                for (int k = 0; k < 8; ++k) acc[cc][k] += wvv[cc] * xv[k];
        }
    }
#pragma unroll
    for (int cc = 0; cc < 8; ++cc) {
        float bb = ba[c0 + cc];
#pragma unroll
        for (int k = 0; k < 8; ++k) {
            float v = acc[cc][k] + bb;
            v = v > 0.0f ? v : 0.0f;
            p1[((size_t)(b * 128 + c0 + cc)) * 16384 + i * 128 + j0 + k] = v;
        }
    }
}

// ---------------------------------------------------------------------------
// 3x3 conv, CIN -> 64, pad 1, relu. Weights from pre-transposed wT
// ([cin][kk][cout]): staging is a contiguous div-free copy. lx staging is
// (ch = tid>>5, lane = tid&31) row passes: coalesced, div-free.
// ---------------------------------------------------------------------------
template <int CIN>
__global__ __launch_bounds__(256) void k_conv3x3(
    const float* __restrict__ in, const float* __restrict__ wT,
    const float* __restrict__ bias, float* __restrict__ out)
{
    __shared__ float lx[8][3 * 132];   // 8 ch x 3 rows, padded cols 0..129
    __shared__ float lwsf[4608];       // [ch*9 + kk][64 couts]
    int i = blockIdx.x, b = blockIdx.y;
    int cg = threadIdx.x >> 4, jg = threadIdx.x & 15;
    int c0 = cg * 4, j0 = jg * 8;
    int sch = threadIdx.x >> 5, sl = threadIdx.x & 31;
    float acc[4][8];
#pragma unroll
    for (int cc = 0; cc < 4; ++cc)
#pragma unroll
        for (int k = 0; k < 8; ++k) acc[cc][k] = 0.0f;

    for (int o0 = 0; o0 < CIN; o0 += 8) {
        __syncthreads();
        {
            const float* src = in + (size_t)(b * CIN + o0 + sch) * 16384;
#pragma unroll
            for (int r = 0; r < 3; ++r) {
                int ii = i + r - 1;
                bool rowok = (ii >= 0) && (ii < 128);
#pragma unroll
                for (int p = 0; p < 5; ++p) {
                    int col = p * 32 + sl;
                    if (col < 130) {
                        int jj = col - 1;
                        float v = 0.0f;
                        if (rowok && jj >= 0 && jj < 128)
                            v = src[ii * 128 + jj];
                        lx[sch][r * 132 + col] = v;
                    }
                }
            }
        }
        {
            const float* wsrc = wT + (size_t)o0 * 576;   // rows (o0*9 .. o0*9+71)
            for (int n = threadIdx.x; n < 4608; n += 256)
                lwsf[n] = wsrc[n];
        }
        __syncthreads();

#pragma unroll 1
        for (int ch = 0; ch < 8; ++ch) {
            float x0[10], x1[10], x2[10];
#pragma unroll
            for (int k = 0; k < 10; ++k) {
                x0[k] = lx[ch][0 * 132 + j0 + k];
                x1[k] = lx[ch][1 * 132 + j0 + k];
                x2[k] = lx[ch][2 * 132 + j0 + k];
            }
#pragma unroll
            for (int cc = 0; cc < 4; ++cc) {
                const float* wp = &lwsf[ch * 576 + c0 + cc];
                float w00 = wp[0],   w01 = wp[64],  w02 = wp[128];
                float w10 = wp[192], w11 = wp[256], w12 = wp[320];
                float w20 = wp[384], w21 = wp[448], w22 = wp[512];
#pragma unroll
                for (int k = 0; k < 8; ++k) {
                    acc[cc][k] += w00 * x0[k] + w01 * x0[k + 1] + w02 * x0[k + 2]
                                + w10 * x1[k] + w11 * x1[k + 1] + w12 * x1[k + 2]
                                + w20 * x2[k] + w21 * x2[k + 1] + w22 * x2[k + 2];
                }
            }
        }
    }
#pragma unroll
    for (int cc = 0; cc < 4; ++cc) {
        float bb = bias[c0 + cc];
#pragma unroll
        for (int k = 0; k < 8; ++k) {
            float v = acc[cc][k] + bb;
            v = v > 0.0f ? v : 0.0f;
            out[((size_t)(b * 64 + c0 + cc) * 128 + i) * 128 + j0 + k] = v;
        }
    }
}

// ---------------------------------------------------------------------------
// conv-d: 1x1, 64 -> 4, sigmoid, scatter to d_out floats
// ---------------------------------------------------------------------------
__global__ __launch_bounds__(256) void k_convd(
    const float* __restrict__ p3, const float* __restrict__ wd,
    const float* __restrict__ bd, float* __restrict__ outp)
{
    __shared__ float lw[256];
    int b = blockIdx.y;
    int ij = blockIdx.x * 256 + threadIdx.x;
    lw[threadIdx.x] = wd[threadIdx.x];
    __syncthreads();
    float a0 = bd[0], a1 = bd[1], a2 = bd[2], a3 = bd[3];
    for (int c = 0; c < 64; ++c) {
        float v = p3[((size_t)(b * 64 + c)) * 16384 + ij];
        a0 += lw[c] * v;
        a1 += lw[64 + c] * v;
        a2 += lw[128 + c] * v;
        a3 += lw[192 + c] * v;
    }
    outp[1536 + (size_t)(b * 2 + 0) * 16384 + ij] = sigmoidf(a2);  // iou ch0
    outp[1536 + (size_t)(b * 2 + 1) * 16384 + ij] = sigmoidf(a3);  // iou ch1
    outp[132608 + (size_t)b * 16384 + ij] = sigmoidf(a0);          // prop_start
    outp[198144 + (size_t)b * 16384 + ij] = sigmoidf(a1);          // prop_end
}

// ---------------------------------------------------------------------------
extern "C" void kernel_launch(void* const* d_in, const int* in_sizes, int n_in,
                              void* d_out, int out_size, void* d_ws, size_t ws_size,
                              hipStream_t stream)
{
    const float* x   = (const float*)d_in[0];
    const float* w1  = (const float*)d_in[1];
    const float* b1  = (const float*)d_in[2];
    const float* w2  = (const float*)d_in[3];
    const float* b2  = (const float*)d_in[4];
    const float* w3  = (const float*)d_in[5];
    const float* b3  = (const float*)d_in[6];
    const float* w3d = (const float*)d_in[7];
    const float* b3d = (const float*)d_in[8];
    const float* wa  = (const float*)d_in[9];
    const float* ba  = (const float*)d_in[10];
    const float* wb  = (const float*)d_in[11];
    const float* bb  = (const float*)d_in[12];
    const float* wc  = (const float*)d_in[13];
    const float* bc  = (const float*)d_in[14];
    const float* wd  = (const float*)d_in[15];
    const float* bd  = (const float*)d_in[16];
    const float* sm  = (const float*)d_in[17];
    float* outp = (float*)d_out;
    char* ws = (char*)d_ws;

    // workspace layout (with aliasing; peak ~127.3 MB)
    float*  h1    = (float*)(ws + 0);              //  1,048,576 B
    float*  h     = (float*)(ws + 1048576);        //    262,144 B
    ushort* h2t   = (ushort*)(ws + 1310720);       // 16,777,216 B
    uint32* ecnt  = (uint32*)(ws + 18087936);      //  2,097,152 B
    uint8_t* et   = (uint8_t*)(ws + 20185088);     //  4,194,304 B
    float*  ewf   = (float*)(ws + 24379392);       // 16,777,216 B (dead after e2)
    uint32* cntij = (uint32*)(ws + 41156608);      //     65,536 B
    int2*   taps  = (int2*)(ws + 41222144);        // 25,165,824 B
    ushort* cm2   = (ushort*)(ws + 66387968);      // 67,108,864 B  [ij][bo]
    float*  p1    = (float*)(ws + 1310720);        // 33,554,432 B (aliases h2t+e-bufs)
    float*  p2    = (float*)(ws + 41222144);       // 16,777,216 B (aliases taps)
    float*  p3    = (float*)(ws + 66387968);       // 16,777,216 B (aliases cm2)
    float*  wbT   = (float*)(ws + 34865152);       //    294,912 B (in dead ewf zone, > p1 end)
    float*  wcT   = (float*)(ws + 35160064);       //    147,456 B (ends < cntij)

    dim3 blk(256);
    k_conv1d_relu<<<dim3(32, 4), blk, 0, stream>>>(x, w1, b1, h1, 200, 400, 512);
    k_conv1d_relu<<<dim3(8, 4), blk, 0, stream>>>(h1, w2, b2, h, 512, 512, 128);
    k_x4<<<1, 512, 0, stream>>>(h, w3, b3, outp);
    k_h2<<<dim3(8, 32, 4), blk, 0, stream>>>(h, w3d, h2t);
    k_e1<<<2048, blk, 0, stream>>>(sm, ecnt, et, ewf);
    k_e2<<<8192, 64, 0, stream>>>(ecnt, et, ewf, cntij, taps);
    k_wt<<<288, blk, 0, stream>>>(wb, wbT, 128);
    k_wt<<<144, blk, 0, stream>>>(wc, wcT, 64);
    k_bm<<<dim3(8, 1024), dim3(64), 0, stream>>>(h2t, taps, cntij, b3d, cm2);
    k_conva<<<dim3(128, 4), blk, 0, stream>>>(cm2, wa, ba, p1);
    k_conv3x3<128><<<dim3(128, 4), blk, 0, stream>>>(p1, wbT, bb, p2);
    k_conv3x3<64><<<dim3(128, 4), blk, 0, stream>>>(p2, wcT, bc, p3);
    k_convd<<<dim3(64, 4), blk, 0, stream>>>(p3, wd, bd, outp);
}